// Round 1
// 363.125 us; speedup vs baseline: 1.2222x; 1.2222x over previous
//
#include <hip/hip_runtime.h>
#include <math.h>

#define NN 100000
#define NE 1600000
#define DD 64
#define NBUK 782          // ceil(NN/128), bucket = dst>>7
#define TILE 8192
#define NTB ((NE + TILE - 1) / TILE)   // 196 partition tiles

typedef __attribute__((ext_vector_type(8))) short short8;
typedef __attribute__((ext_vector_type(4))) float f32x4;

__device__ __forceinline__ float gelu_exact(float v) {
    return 0.5f * v * (1.0f + erff(v * 0.7071067811865475f));
}

__device__ __forceinline__ unsigned short f2bf(float f) {   // RNE
    unsigned u = __float_as_uint(f);
    return (unsigned short)((u + 0x7FFFu + ((u >> 16) & 1u)) >> 16);
}
__device__ __forceinline__ float bf2f(unsigned short h) {
    return __uint_as_float((unsigned)h << 16);
}
__device__ __forceinline__ void split8(const float* a, short8& hi, short8& lo) {
    float4 x0 = *(const float4*)a;
    float4 x1 = *(const float4*)(a + 4);
    float v[8] = {x0.x, x0.y, x0.z, x0.w, x1.x, x1.y, x1.z, x1.w};
    #pragma unroll
    for (int i = 0; i < 8; ++i) {
        unsigned short h = f2bf(v[i]);
        hi[i] = (short)h;
        lo[i] = (short)f2bf(v[i] - bf2f(h));
    }
}

__device__ __forceinline__ float wave_sum64(float v) {
    #pragma unroll
    for (int o = 32; o > 0; o >>= 1) v += __shfl_xor(v, o);
    return v;
}

// K0P: build bf16 hi/lo split weight buffers
__global__ __launch_bounds__(256) void k0prep(
    const float* __restrict__ Wp, const float* __restrict__ Wn,
    const float* __restrict__ w1, const float* __restrict__ w2,
    const float* __restrict__ cf,
    unsigned short* __restrict__ wh, unsigned short* __restrict__ wl)
{
    int t = blockIdx.x * 256 + threadIdx.x;   // 24576 total
    float alpha = 1.0f / (1.0f + __expf(-cf[0]));
    float beta  = 1.0f - alpha;
    float v;
    if (t < 8192) {
        int d = t >> 7, k = t & 127;
        v = (k < 64) ? alpha * Wp[d * 64 + k] : beta * Wn[d * 64 + (k - 64)];
    } else if (t < 16384) {
        v = w1[t - 8192];
    } else {
        v = w2[t - 16384];
    }
    unsigned short h = f2bf(v);
    wh[t] = h;
    wl[t] = f2bf(v - bf2f(h));
}

// K1: per-node attention projection -> exp(s1). s2[dst] cancels in the
// segment softmax (constant per segment); |s1| <= ~5 so exp never overflows.
__global__ __launch_bounds__(256) void k1_scores(
    const float* __restrict__ x, const float* __restrict__ attw,
    float* __restrict__ es1)
{
    int n = blockIdx.x * 256 + threadIdx.x;
    if (n >= NN) return;
    const float4* x4 = (const float4*)(x + (size_t)n * DD);
    float a = 0.f;
    #pragma unroll
    for (int i = 0; i < DD/4; ++i) {
        float4 v = x4[i];
        a += v.x*attw[4*i+0] + v.y*attw[4*i+1] + v.z*attw[4*i+2] + v.w*attw[4*i+3];
    }
    es1[n] = __expf(a);
}

// KH: tiled coarse histogram — per-block LDS hist, then <=782 global atomics/block
__global__ __launch_bounds__(256) void kh_tiled(
    const int* __restrict__ ei, int* __restrict__ bcount)
{
    __shared__ int hist[NBUK];
    for (int i = threadIdx.x; i < NBUK; i += 256) hist[i] = 0;
    __syncthreads();
    int base = blockIdx.x * TILE;
    int end  = min(base + TILE, NE);
    for (int e = base + threadIdx.x; e < end; e += 256)
        atomicAdd(&hist[ei[NE + e] >> 7], 1);
    __syncthreads();
    for (int i = threadIdx.x; i < NBUK; i += 256) {
        int c = hist[i];
        if (c) atomicAdd(bcount + i, c);
    }
}

// KBS: single-block exclusive scan of 782 bucket counts -> bbase, bpos
__global__ __launch_bounds__(1024) void ks_bscan(
    const int* __restrict__ bcount, int* __restrict__ bbase, int* __restrict__ bpos)
{
    __shared__ int sa[1024], sb[1024];
    int t = threadIdx.x;
    int v = (t < NBUK) ? bcount[t] : 0;
    sa[t] = v;
    __syncthreads();
    int* s = sa; int* d = sb;
    #pragma unroll
    for (int o = 1; o < 1024; o <<= 1) {
        d[t] = s[t] + ((t >= o) ? s[t - o] : 0);
        __syncthreads();
        int* tmp = s; s = d; d = tmp;
    }
    if (t < NBUK) {
        int excl = s[t] - v;
        bbase[t] = excl;
        bpos[t]  = excl;
    }
    if (t == 0) bbase[NBUK] = NE;
}

// KSCAT1: tiled coarse partition (per-block LDS hist -> one reservation atomic
// per (block,bucket) -> LDS-ticket scatter).
__global__ __launch_bounds__(256) void kscat1(
    const int* __restrict__ ei, const float* __restrict__ rf,
    int* __restrict__ bpos, uint2* __restrict__ tmp)
{
    __shared__ int hist[NBUK];
    __shared__ int gbase[NBUK];
    for (int i = threadIdx.x; i < NBUK; i += 256) hist[i] = 0;
    __syncthreads();
    int base = blockIdx.x * TILE;
    int end  = min(base + TILE, NE);
    for (int e = base + threadIdx.x; e < end; e += 256)
        atomicAdd(&hist[ei[NE + e] >> 7], 1);
    __syncthreads();
    for (int i = threadIdx.x; i < NBUK; i += 256) {
        int c = hist[i];
        gbase[i] = c ? atomicAdd(bpos + i, c) : 0;
        hist[i] = 0;                      // reuse as ticket counter
    }
    __syncthreads();
    for (int e = base + threadIdx.x; e < end; e += 256) {
        int src = ei[e];
        int dst = ei[NE + e];
        int b = dst >> 7;
        int t = atomicAdd(&hist[b], 1);
        tmp[gbase[b] + t] =
            make_uint2((unsigned)src | ((unsigned)(dst & 127) << 17),
                       __float_as_uint(rf[e]));
    }
}

// KSCAT2: block-per-bucket fine sort: local histogram -> scan -> off[] + final scatter
__global__ __launch_bounds__(256) void kscat2(
    const uint2* __restrict__ tmp, const int* __restrict__ bbase,
    int* __restrict__ off, uint2* __restrict__ sorted)
{
    __shared__ int hist[128], scn[128], tick[128];
    int b   = blockIdx.x;
    int tid = threadIdx.x;
    int s = bbase[b], e = bbase[b + 1];

    if (tid < 128) { hist[tid] = 0; tick[tid] = 0; }
    __syncthreads();

    for (int i = s + tid; i < e; i += 256)
        atomicAdd(&hist[tmp[i].x >> 17], 1);
    __syncthreads();

    if (tid < 128) scn[tid] = hist[tid];
    __syncthreads();
    #pragma unroll
    for (int o = 1; o < 128; o <<= 1) {
        int v = (tid < 128 && tid >= o) ? scn[tid - o] : 0;
        __syncthreads();
        if (tid < 128) scn[tid] += v;
        __syncthreads();
    }

    int nb0 = b * 128;
    if (tid < 128 && nb0 + tid < NN) off[nb0 + tid] = s + scn[tid] - hist[tid];
    if (b == NBUK - 1 && tid == 0) off[NN] = NE;
    __syncthreads();

    for (int i = s + tid; i < e; i += 256) {
        uint2 pr = tmp[i];
        int l = pr.x >> 17;
        int t = atomicAdd(&tick[l], 1);
        int p = s + (scn[l] - hist[l]) + t;
        sorted[p] = make_uint2(pr.x & 0x1FFFFu, pr.y);
    }
}

// K4A: wave-per-node fused softmax + aggregation, SINGLE PASS.
// Softmax uses exp(s1) directly (no max pass, no s2 — both cancel/are safe).
__global__ __launch_bounds__(256) void k4a_agg(
    const float2* __restrict__ sorted, const int* __restrict__ off,
    const float* __restrict__ es1,
    const float* __restrict__ x, float* __restrict__ uv)
{
    int lane = threadIdx.x & 63;
    int n = blockIdx.x * 4 + (threadIdx.x >> 6);
    int r0 = off[n], r1 = off[n + 1];

    float den = 0.f, u = 0.f, v = 0.f;
    for (int base = r0; base < r1; base += 64) {
        int idx = base + lane;
        int cnt = min(64, r1 - base);
        int srcl = 0; float rfl = 0.f, el = 0.f;
        if (idx < r1) {
            float2 p = sorted[idx];
            srcl = __float_as_int(p.x);
            rfl  = p.y;
            el   = es1[srcl];
        }
        den += wave_sum64(el);
        int j = 0;
        for (; j + 4 <= cnt; j += 4) {
            int   a0 = __shfl(srcl, j+0), a1 = __shfl(srcl, j+1);
            int   a2 = __shfl(srcl, j+2), a3 = __shfl(srcl, j+3);
            float e0 = __shfl(el, j+0), e1 = __shfl(el, j+1);
            float e2 = __shfl(el, j+2), e3 = __shfl(el, j+3);
            float f0 = __shfl(rfl, j+0), f1 = __shfl(rfl, j+1);
            float f2 = __shfl(rfl, j+2), f3 = __shfl(rfl, j+3);
            float x0 = x[(size_t)a0 * DD + lane];
            float x1 = x[(size_t)a1 * DD + lane];
            float x2 = x[(size_t)a2 * DD + lane];
            float x3 = x[(size_t)a3 * DD + lane];
            v += e0*x0 + e1*x1 + e2*x2 + e3*x3;
            u += e0*f0*x0 + e1*f1*x1 + e2*f2*x2 + e3*f3*x3;
        }
        for (; j < cnt; ++j) {
            int   sj = __shfl(srcl, j);
            float ej = __shfl(el,   j);
            float fj = __shfl(rfl,  j);
            float xv = x[(size_t)sj * DD + lane];
            v += ej * xv;
            u += ej * fj * xv;
        }
    }
    float inv = (r1 > r0) ? 1.f / den : 0.f;
    uv[(size_t)n * 2*DD + lane]      = u * inv;
    uv[(size_t)n * 2*DD + DD + lane] = v * inv;
}

// K4B+LN1 fused: agg = uv @ Bmix (MFMA split-bf16), then h = LN1(gelu(agg)+x)
// in-register (row lives across the 16 lanes of a quad; shfl_xor o<16 reduces).
__global__ __launch_bounds__(256) void k4b_ln1(
    const float* __restrict__ uv, const unsigned short* __restrict__ wh,
    const unsigned short* __restrict__ wl, const float* __restrict__ x,
    const float* __restrict__ g1, const float* __restrict__ be1,
    float* __restrict__ hbuf)
{
    int lane = threadIdx.x & 63;
    int wv   = threadIdx.x >> 6;
    int quad = lane >> 4, l16 = lane & 15;
    int nb = blockIdx.x * 64 + wv * 16;
    const float* arow = uv + (size_t)min(nb + l16, NN - 1) * 128;

    f32x4 acc[4] = {};
    #pragma unroll
    for (int ks = 0; ks < 4; ++ks) {
        int k0 = ks * 32 + quad * 8;
        short8 ah, al;
        split8(arow + k0, ah, al);
        #pragma unroll
        for (int nt = 0; nt < 4; ++nt) {
            short8 bh = *(const short8*)(wh + (size_t)(nt*16 + l16)*128 + k0);
            short8 bl = *(const short8*)(wl + (size_t)(nt*16 + l16)*128 + k0);
            acc[nt] = __builtin_amdgcn_mfma_f32_16x16x32_bf16(ah, bh, acc[nt], 0, 0, 0);
            acc[nt] = __builtin_amdgcn_mfma_f32_16x16x32_bf16(al, bh, acc[nt], 0, 0, 0);
            acc[nt] = __builtin_amdgcn_mfma_f32_16x16x32_bf16(ah, bl, acc[nt], 0, 0, 0);
        }
    }
    #pragma unroll
    for (int r = 0; r < 4; ++r) {
        int n = nb + quad * 4 + r;
        size_t nld = (size_t)min(n, NN - 1) * 64;
        float hv[4];
        #pragma unroll
        for (int nt = 0; nt < 4; ++nt)
            hv[nt] = gelu_exact(acc[nt][r]) + x[nld + nt*16 + l16];
        float s = hv[0] + hv[1] + hv[2] + hv[3];
        #pragma unroll
        for (int o = 1; o < 16; o <<= 1) s += __shfl_xor(s, o);
        float mu = s * (1.0f/64.0f);
        float q = 0.f;
        #pragma unroll
        for (int nt = 0; nt < 4; ++nt) { float t = hv[nt] - mu; q += t*t; }
        #pragma unroll
        for (int o = 1; o < 16; o <<= 1) q += __shfl_xor(q, o);
        float rs = rsqrtf(q * (1.0f/64.0f) + 1e-5f);
        if (n < NN) {
            #pragma unroll
            for (int nt = 0; nt < 4; ++nt) {
                int c = nt*16 + l16;
                hbuf[(size_t)n * 64 + c] = (hv[nt] - mu) * rs * g1[c] + be1[c];
            }
        }
    }
}

// K5 fused MLP: GEMM1+gelu -> LDS (per-wave, padded rows) -> GEMM2 ->
// residual(+b2) + LN2 epilogue. No __syncthreads needed (wave-private LDS tile).
#define GP 132   // 128 + 4 pad: keeps 16B alignment, breaks 32-bank stride
__global__ __launch_bounds__(256) void k5_mlp(
    const float* __restrict__ hbuf,
    const unsigned short* __restrict__ w1h, const unsigned short* __restrict__ w1l,
    const float* __restrict__ bb1,
    const unsigned short* __restrict__ w2h, const unsigned short* __restrict__ w2l,
    const float* __restrict__ bb2,
    const float* __restrict__ g2, const float* __restrict__ be2,
    float* __restrict__ out)
{
    __shared__ float Gl[4][16][GP];
    int lane = threadIdx.x & 63;
    int wv   = threadIdx.x >> 6;
    int quad = lane >> 4, l16 = lane & 15;
    int nb = blockIdx.x * 64 + wv * 16;
    const float* arow = hbuf + (size_t)min(nb + l16, NN - 1) * 64;

    // GEMM1: [16x64] @ w1^T -> 16x128
    f32x4 acc1[8] = {};
    #pragma unroll
    for (int ks = 0; ks < 2; ++ks) {
        int k0 = ks * 32 + quad * 8;
        short8 ah, al;
        split8(arow + k0, ah, al);
        #pragma unroll
        for (int nt = 0; nt < 8; ++nt) {
            short8 bh = *(const short8*)(w1h + (size_t)(nt*16 + l16)*64 + k0);
            short8 bl = *(const short8*)(w1l + (size_t)(nt*16 + l16)*64 + k0);
            acc1[nt] = __builtin_amdgcn_mfma_f32_16x16x32_bf16(ah, bh, acc1[nt], 0, 0, 0);
            acc1[nt] = __builtin_amdgcn_mfma_f32_16x16x32_bf16(al, bh, acc1[nt], 0, 0, 0);
            acc1[nt] = __builtin_amdgcn_mfma_f32_16x16x32_bf16(ah, bl, acc1[nt], 0, 0, 0);
        }
    }
    // gelu + b1 -> LDS (wave-private 16x128 tile)
    #pragma unroll
    for (int nt = 0; nt < 8; ++nt) {
        float b1v = bb1[nt*16 + l16];
        #pragma unroll
        for (int r = 0; r < 4; ++r)
            Gl[wv][quad*4 + r][nt*16 + l16] = gelu_exact(acc1[nt][r] + b1v);
    }

    // GEMM2: [16x128] @ w2^T -> 16x64
    f32x4 acc2[4] = {};
    #pragma unroll
    for (int ks = 0; ks < 4; ++ks) {
        int k0 = ks * 32 + quad * 8;
        short8 ah, al;
        split8(&Gl[wv][l16][k0], ah, al);
        #pragma unroll
        for (int nt = 0; nt < 4; ++nt) {
            short8 bh = *(const short8*)(w2h + (size_t)(nt*16 + l16)*128 + k0);
            short8 bl = *(const short8*)(w2l + (size_t)(nt*16 + l16)*128 + k0);
            acc2[nt] = __builtin_amdgcn_mfma_f32_16x16x32_bf16(ah, bh, acc2[nt], 0, 0, 0);
            acc2[nt] = __builtin_amdgcn_mfma_f32_16x16x32_bf16(al, bh, acc2[nt], 0, 0, 0);
            acc2[nt] = __builtin_amdgcn_mfma_f32_16x16x32_bf16(ah, bl, acc2[nt], 0, 0, 0);
        }
    }

    // epilogue: m = acc2 + hbuf + b2; out = LN2(m)
    #pragma unroll
    for (int r = 0; r < 4; ++r) {
        int n = nb + quad * 4 + r;
        size_t nld = (size_t)min(n, NN - 1) * 64;
        float mv[4];
        #pragma unroll
        for (int nt = 0; nt < 4; ++nt) {
            int c = nt*16 + l16;
            mv[nt] = acc2[nt][r] + hbuf[nld + c] + bb2[c];
        }
        float s = mv[0] + mv[1] + mv[2] + mv[3];
        #pragma unroll
        for (int o = 1; o < 16; o <<= 1) s += __shfl_xor(s, o);
        float mu = s * (1.0f/64.0f);
        float q = 0.f;
        #pragma unroll
        for (int nt = 0; nt < 4; ++nt) { float t = mv[nt] - mu; q += t*t; }
        #pragma unroll
        for (int o = 1; o < 16; o <<= 1) q += __shfl_xor(q, o);
        float rs = rsqrtf(q * (1.0f/64.0f) + 1e-5f);
        if (n < NN) {
            #pragma unroll
            for (int nt = 0; nt < 4; ++nt) {
                int c = nt*16 + l16;
                out[(size_t)n * 64 + c] = (mv[nt] - mu) * rs * g2[c] + be2[c];
            }
        }
    }
}

extern "C" void kernel_launch(void* const* d_in, const int* in_sizes, int n_in,
                              void* d_out, int out_size, void* d_ws, size_t ws_size,
                              hipStream_t stream) {
    const float* x    = (const float*)d_in[0];
    const int*   ei   = (const int*)d_in[1];
    const float* rf   = (const float*)d_in[2];
    const float* Wp   = (const float*)d_in[3];
    const float* Wn   = (const float*)d_in[4];
    const float* attw = (const float*)d_in[5];
    const float* cf   = (const float*)d_in[6];
    const float* w1   = (const float*)d_in[7];
    const float* b1   = (const float*)d_in[8];
    const float* w2   = (const float*)d_in[9];
    const float* b2   = (const float*)d_in[10];
    const float* g1   = (const float*)d_in[11];
    const float* be1  = (const float*)d_in[12];
    const float* g2   = (const float*)d_in[13];
    const float* be2  = (const float*)d_in[14];
    float* out = (float*)d_out;

    float* ws = (float*)d_ws;
    float*  es1    = ws;                                   // NN
    float*  uv     = es1 + NN;                             // NN*128
    float*  hbuf   = uv + (size_t)NN * 128;                // NN*64
    unsigned short* wh = (unsigned short*)(hbuf + (size_t)NN * 64);  // 24576 u16
    unsigned short* wl = wh + 24576;                                 // 24576 u16
    uint2*  sorted = (uint2*)(wl + 24576);                 // NE uint2
    int*    off    = (int*)(sorted + NE);                  // NN+1
    int*    bcount = off + NN + 1;                         // NBUK
    int*    bbase  = bcount + NBUK;                        // NBUK+1
    int*    bpos   = bbase + NBUK + 1;                     // NBUK
    uint2*  tmp    = (uint2*)uv;                           // alias: uv written later by k4a

    const unsigned short* wmh = wh;          const unsigned short* wml = wl;
    const unsigned short* w1h = wh + 8192;   const unsigned short* w1l = wl + 8192;
    const unsigned short* w2h = wh + 16384;  const unsigned short* w2l = wl + 16384;

    hipMemsetAsync(bcount, 0, NBUK * sizeof(int), stream);

    k0prep    <<<96, 256, 0, stream>>>(Wp, Wn, w1, w2, cf, wh, wl);
    k1_scores <<<(NN+255)/256, 256, 0, stream>>>(x, attw, es1);
    kh_tiled  <<<NTB, 256, 0, stream>>>(ei, bcount);
    ks_bscan  <<<1, 1024, 0, stream>>>(bcount, bbase, bpos);
    kscat1    <<<NTB, 256, 0, stream>>>(ei, rf, bpos, tmp);
    kscat2    <<<NBUK, 256, 0, stream>>>(tmp, bbase, off, sorted);
    k4a_agg   <<<NN/4, 256, 0, stream>>>((const float2*)sorted, off, es1, x, uv);
    k4b_ln1   <<<(NN+63)/64, 256, 0, stream>>>(uv, wmh, wml, x, g1, be1, hbuf);
    k5_mlp    <<<(NN+63)/64, 256, 0, stream>>>(hbuf, w1h, w1l, b1, w2h, w2l, b2, g2, be2, out);
}

// Round 2
// 340.283 us; speedup vs baseline: 1.3042x; 1.0671x over previous
//
#include <hip/hip_runtime.h>
#include <math.h>

#define NN 100000
#define NE 1600000
#define DD 64
#define NBUK 782          // ceil(NN/128), bucket = dst>>7
#define TILE 8192
#define NTB ((NE + TILE - 1) / TILE)   // 196 partition tiles

typedef __attribute__((ext_vector_type(8))) short short8;
typedef __attribute__((ext_vector_type(4))) float f32x4;

__device__ __forceinline__ float gelu_exact(float v) {
    return 0.5f * v * (1.0f + erff(v * 0.7071067811865475f));
}

__device__ __forceinline__ unsigned short f2bf(float f) {   // RNE
    unsigned u = __float_as_uint(f);
    return (unsigned short)((u + 0x7FFFu + ((u >> 16) & 1u)) >> 16);
}
__device__ __forceinline__ float bf2f(unsigned short h) {
    return __uint_as_float((unsigned)h << 16);
}
__device__ __forceinline__ void split8(const float* a, short8& hi, short8& lo) {
    float4 x0 = *(const float4*)a;
    float4 x1 = *(const float4*)(a + 4);
    float v[8] = {x0.x, x0.y, x0.z, x0.w, x1.x, x1.y, x1.z, x1.w};
    #pragma unroll
    for (int i = 0; i < 8; ++i) {
        unsigned short h = f2bf(v[i]);
        hi[i] = (short)h;
        lo[i] = (short)f2bf(v[i] - bf2f(h));
    }
}

__device__ __forceinline__ float wave_sum64(float v) {
    #pragma unroll
    for (int o = 32; o > 0; o >>= 1) v += __shfl_xor(v, o);
    return v;
}

// K0P: build bf16 hi/lo split weight buffers
__global__ __launch_bounds__(256) void k0prep(
    const float* __restrict__ Wp, const float* __restrict__ Wn,
    const float* __restrict__ w1, const float* __restrict__ w2,
    const float* __restrict__ cf,
    unsigned short* __restrict__ wh, unsigned short* __restrict__ wl)
{
    int t = blockIdx.x * 256 + threadIdx.x;   // 24576 total
    float alpha = 1.0f / (1.0f + __expf(-cf[0]));
    float beta  = 1.0f - alpha;
    float v;
    if (t < 8192) {
        int d = t >> 7, k = t & 127;
        v = (k < 64) ? alpha * Wp[d * 64 + k] : beta * Wn[d * 64 + (k - 64)];
    } else if (t < 16384) {
        v = w1[t - 8192];
    } else {
        v = w2[t - 16384];
    }
    unsigned short h = f2bf(v);
    wh[t] = h;
    wl[t] = f2bf(v - bf2f(h));
}

// K1: per-node attention projection -> exp(s1). s2[dst] cancels in the
// segment softmax (constant per segment); |s1| <= ~5 so exp never overflows.
__global__ __launch_bounds__(256) void k1_scores(
    const float* __restrict__ x, const float* __restrict__ attw,
    float* __restrict__ es1)
{
    int n = blockIdx.x * 256 + threadIdx.x;
    if (n >= NN) return;
    const float4* x4 = (const float4*)(x + (size_t)n * DD);
    float a = 0.f;
    #pragma unroll
    for (int i = 0; i < DD/4; ++i) {
        float4 v = x4[i];
        a += v.x*attw[4*i+0] + v.y*attw[4*i+1] + v.z*attw[4*i+2] + v.w*attw[4*i+3];
    }
    es1[n] = __expf(a);
}

// KH: tiled coarse histogram — per-block LDS hist, then <=782 global atomics/block
__global__ __launch_bounds__(256) void kh_tiled(
    const int* __restrict__ ei, int* __restrict__ bcount)
{
    __shared__ int hist[NBUK];
    for (int i = threadIdx.x; i < NBUK; i += 256) hist[i] = 0;
    __syncthreads();
    int base = blockIdx.x * TILE;
    int end  = min(base + TILE, NE);
    for (int e = base + threadIdx.x; e < end; e += 256)
        atomicAdd(&hist[ei[NE + e] >> 7], 1);
    __syncthreads();
    for (int i = threadIdx.x; i < NBUK; i += 256) {
        int c = hist[i];
        if (c) atomicAdd(bcount + i, c);
    }
}

// KBS: single-block exclusive scan of 782 bucket counts -> bbase, bpos
__global__ __launch_bounds__(1024) void ks_bscan(
    const int* __restrict__ bcount, int* __restrict__ bbase, int* __restrict__ bpos)
{
    __shared__ int sa[1024], sb[1024];
    int t = threadIdx.x;
    int v = (t < NBUK) ? bcount[t] : 0;
    sa[t] = v;
    __syncthreads();
    int* s = sa; int* d = sb;
    #pragma unroll
    for (int o = 1; o < 1024; o <<= 1) {
        d[t] = s[t] + ((t >= o) ? s[t - o] : 0);
        __syncthreads();
        int* tmp = s; s = d; d = tmp;
    }
    if (t < NBUK) {
        int excl = s[t] - v;
        bbase[t] = excl;
        bpos[t]  = excl;
    }
    if (t == 0) bbase[NBUK] = NE;
}

// KSCAT1: tiled coarse partition (per-block LDS hist -> one reservation atomic
// per (block,bucket) -> LDS-ticket scatter).
__global__ __launch_bounds__(256) void kscat1(
    const int* __restrict__ ei, const float* __restrict__ rf,
    int* __restrict__ bpos, uint2* __restrict__ tmp)
{
    __shared__ int hist[NBUK];
    __shared__ int gbase[NBUK];
    for (int i = threadIdx.x; i < NBUK; i += 256) hist[i] = 0;
    __syncthreads();
    int base = blockIdx.x * TILE;
    int end  = min(base + TILE, NE);
    for (int e = base + threadIdx.x; e < end; e += 256)
        atomicAdd(&hist[ei[NE + e] >> 7], 1);
    __syncthreads();
    for (int i = threadIdx.x; i < NBUK; i += 256) {
        int c = hist[i];
        gbase[i] = c ? atomicAdd(bpos + i, c) : 0;
        hist[i] = 0;                      // reuse as ticket counter
    }
    __syncthreads();
    for (int e = base + threadIdx.x; e < end; e += 256) {
        int src = ei[e];
        int dst = ei[NE + e];
        int b = dst >> 7;
        int t = atomicAdd(&hist[b], 1);
        tmp[gbase[b] + t] =
            make_uint2((unsigned)src | ((unsigned)(dst & 127) << 17),
                       __float_as_uint(rf[e]));
    }
}

// KSCAT2: block-per-bucket fine sort: local histogram -> scan -> off[] + final scatter
__global__ __launch_bounds__(256) void kscat2(
    const uint2* __restrict__ tmp, const int* __restrict__ bbase,
    int* __restrict__ off, uint2* __restrict__ sorted)
{
    __shared__ int hist[128], scn[128], tick[128];
    int b   = blockIdx.x;
    int tid = threadIdx.x;
    int s = bbase[b], e = bbase[b + 1];

    if (tid < 128) { hist[tid] = 0; tick[tid] = 0; }
    __syncthreads();

    for (int i = s + tid; i < e; i += 256)
        atomicAdd(&hist[tmp[i].x >> 17], 1);
    __syncthreads();

    if (tid < 128) scn[tid] = hist[tid];
    __syncthreads();
    #pragma unroll
    for (int o = 1; o < 128; o <<= 1) {
        int v = (tid < 128 && tid >= o) ? scn[tid - o] : 0;
        __syncthreads();
        if (tid < 128) scn[tid] += v;
        __syncthreads();
    }

    int nb0 = b * 128;
    if (tid < 128 && nb0 + tid < NN) off[nb0 + tid] = s + scn[tid] - hist[tid];
    if (b == NBUK - 1 && tid == 0) off[NN] = NE;
    __syncthreads();

    for (int i = s + tid; i < e; i += 256) {
        uint2 pr = tmp[i];
        int l = pr.x >> 17;
        int t = atomicAdd(&tick[l], 1);
        int p = s + (scn[l] - hist[l]) + t;
        sorted[p] = make_uint2(pr.x & 0x1FFFFu, pr.y);
    }
}

// K4A: wave-per-node fused softmax + aggregation, single pass.
__global__ __launch_bounds__(256) void k4a_agg(
    const float2* __restrict__ sorted, const int* __restrict__ off,
    const float* __restrict__ es1,
    const float* __restrict__ x, float* __restrict__ uv)
{
    int lane = threadIdx.x & 63;
    int n = blockIdx.x * 4 + (threadIdx.x >> 6);
    int r0 = off[n], r1 = off[n + 1];

    float den = 0.f, u = 0.f, v = 0.f;
    for (int base = r0; base < r1; base += 64) {
        int idx = base + lane;
        int cnt = min(64, r1 - base);
        int srcl = 0; float rfl = 0.f, el = 0.f;
        if (idx < r1) {
            float2 p = sorted[idx];
            srcl = __float_as_int(p.x);
            rfl  = p.y;
            el   = es1[srcl];
        }
        den += wave_sum64(el);
        int j = 0;
        for (; j + 4 <= cnt; j += 4) {
            int   a0 = __shfl(srcl, j+0), a1 = __shfl(srcl, j+1);
            int   a2 = __shfl(srcl, j+2), a3 = __shfl(srcl, j+3);
            float e0 = __shfl(el, j+0), e1 = __shfl(el, j+1);
            float e2 = __shfl(el, j+2), e3 = __shfl(el, j+3);
            float f0 = __shfl(rfl, j+0), f1 = __shfl(rfl, j+1);
            float f2 = __shfl(rfl, j+2), f3 = __shfl(rfl, j+3);
            float x0 = x[(size_t)a0 * DD + lane];
            float x1 = x[(size_t)a1 * DD + lane];
            float x2 = x[(size_t)a2 * DD + lane];
            float x3 = x[(size_t)a3 * DD + lane];
            v += e0*x0 + e1*x1 + e2*x2 + e3*x3;
            u += e0*f0*x0 + e1*f1*x1 + e2*f2*x2 + e3*f3*x3;
        }
        for (; j < cnt; ++j) {
            int   sj = __shfl(srcl, j);
            float ej = __shfl(el,   j);
            float fj = __shfl(rfl,  j);
            float xv = x[(size_t)sj * DD + lane];
            v += ej * xv;
            u += ej * fj * xv;
        }
    }
    float inv = (r1 > r0) ? 1.f / den : 0.f;
    uv[(size_t)n * 2*DD + lane]      = u * inv;
    uv[(size_t)n * 2*DD + DD + lane] = v * inv;
}

// K4B5: fully fused epilogue chain, one kernel per 64 nodes:
//   GEMM0 (uv@Bmix) -> gelu+residual+LN1 in-register (h kept in VGPRs)
//   -> h through 16x68 LDS tile (transpose to A-layout only)
//   -> GEMM1 chunked (4 x 32 cols) -> gelu -> 16x36 double-buffered LDS chunk
//   -> GEMM2 partial accumulate -> +h residual +b2 -> LN2 -> out.
// LDS 18432 B/block (union: h-tile reused as G chunks) -> 8 blocks/CU ceiling.
// All LDS strides (68, 36 floats) verified conflict-free for b128 reads.
__global__ __launch_bounds__(256, 4) void k4b5(
    const float* __restrict__ uv,
    const unsigned short* __restrict__ wh, const unsigned short* __restrict__ wl,
    const float* __restrict__ x,
    const float* __restrict__ g1, const float* __restrict__ be1,
    const float* __restrict__ bb1, const float* __restrict__ bb2,
    const float* __restrict__ g2, const float* __restrict__ be2,
    float* __restrict__ out)
{
    union Tile {
        float h[16][68];      // 4352 B: LN1 output, read as GEMM1 A-frags
        float g[2][16][36];   // 4608 B: double-buffered G chunks (32 cols each)
    };
    __shared__ Tile T[4];

    const unsigned short* wmh = wh;          const unsigned short* wml = wl;
    const unsigned short* w1h = wh + 8192;   const unsigned short* w1l = wl + 8192;
    const unsigned short* w2h = wh + 16384;  const unsigned short* w2l = wl + 16384;

    int lane = threadIdx.x & 63;
    int wv   = threadIdx.x >> 6;
    int quad = lane >> 4, l16 = lane & 15;
    int nb = blockIdx.x * 64 + wv * 16;
    const float* arow = uv + (size_t)min(nb + l16, NN - 1) * 128;

    // ---- GEMM0: agg = uv[16x128] @ Bmix^T -> 16x64 (C-layout) ----
    f32x4 acc0[4] = {};
    #pragma unroll
    for (int ks = 0; ks < 4; ++ks) {
        int k0 = ks * 32 + quad * 8;
        short8 ah, al;
        split8(arow + k0, ah, al);
        #pragma unroll
        for (int nt = 0; nt < 4; ++nt) {
            short8 bh = *(const short8*)(wmh + (size_t)(nt*16 + l16)*128 + k0);
            short8 bl = *(const short8*)(wml + (size_t)(nt*16 + l16)*128 + k0);
            acc0[nt] = __builtin_amdgcn_mfma_f32_16x16x32_bf16(ah, bh, acc0[nt], 0, 0, 0);
            acc0[nt] = __builtin_amdgcn_mfma_f32_16x16x32_bf16(al, bh, acc0[nt], 0, 0, 0);
            acc0[nt] = __builtin_amdgcn_mfma_f32_16x16x32_bf16(ah, bl, acc0[nt], 0, 0, 0);
        }
    }

    // ---- gelu + residual + LN1; keep hn in regs, stage into LDS h-tile ----
    float hn[4][4];   // [r][nt]  (C-layout: row quad*4+r, col nt*16+l16)
    #pragma unroll
    for (int r = 0; r < 4; ++r) {
        int n = nb + quad * 4 + r;
        size_t nld = (size_t)min(n, NN - 1) * 64;
        float hv[4];
        #pragma unroll
        for (int nt = 0; nt < 4; ++nt)
            hv[nt] = gelu_exact(acc0[nt][r]) + x[nld + nt*16 + l16];
        float s = hv[0] + hv[1] + hv[2] + hv[3];
        #pragma unroll
        for (int o = 1; o < 16; o <<= 1) s += __shfl_xor(s, o);
        float mu = s * (1.0f/64.0f);
        float q = 0.f;
        #pragma unroll
        for (int nt = 0; nt < 4; ++nt) { float t = hv[nt] - mu; q += t*t; }
        #pragma unroll
        for (int o = 1; o < 16; o <<= 1) q += __shfl_xor(q, o);
        float rs = rsqrtf(q * (1.0f/64.0f) + 1e-5f);
        #pragma unroll
        for (int nt = 0; nt < 4; ++nt) {
            int c = nt*16 + l16;
            hn[r][nt] = (hv[nt] - mu) * rs * g1[c] + be1[c];
            T[wv].h[quad*4 + r][c] = hn[r][nt];
        }
    }

    // ---- A1 fragments (row l16 of h) — read once; h-tile dead afterwards ----
    short8 ah1[2], al1[2];
    #pragma unroll
    for (int ks = 0; ks < 2; ++ks)
        split8(&T[wv].h[l16][ks*32 + quad*8], ah1[ks], al1[ks]);

    // ---- chunked GEMM1 -> gelu -> LDS chunk -> GEMM2 partial ----
    f32x4 acc2[4] = {};
    #pragma unroll
    for (int c = 0; c < 4; ++c) {
        f32x4 a1[2] = {};
        #pragma unroll
        for (int ks = 0; ks < 2; ++ks) {
            int k0 = ks * 32 + quad * 8;
            #pragma unroll
            for (int t = 0; t < 2; ++t) {
                int nt1 = 2*c + t;
                short8 bh = *(const short8*)(w1h + (size_t)(nt1*16 + l16)*64 + k0);
                short8 bl = *(const short8*)(w1l + (size_t)(nt1*16 + l16)*64 + k0);
                a1[t] = __builtin_amdgcn_mfma_f32_16x16x32_bf16(ah1[ks], bh, a1[t], 0, 0, 0);
                a1[t] = __builtin_amdgcn_mfma_f32_16x16x32_bf16(al1[ks], bh, a1[t], 0, 0, 0);
                a1[t] = __builtin_amdgcn_mfma_f32_16x16x32_bf16(ah1[ks], bl, a1[t], 0, 0, 0);
            }
        }
        #pragma unroll
        for (int t = 0; t < 2; ++t) {
            float b1v = bb1[(2*c + t)*16 + l16];
            #pragma unroll
            for (int r = 0; r < 4; ++r)
                T[wv].g[c & 1][quad*4 + r][t*16 + l16] = gelu_exact(a1[t][r] + b1v);
        }
        short8 ah2, al2;
        split8(&T[wv].g[c & 1][l16][quad*8], ah2, al2);
        #pragma unroll
        for (int nt2 = 0; nt2 < 4; ++nt2) {
            int kk = c*32 + quad*8;
            short8 bh = *(const short8*)(w2h + (size_t)(nt2*16 + l16)*128 + kk);
            short8 bl = *(const short8*)(w2l + (size_t)(nt2*16 + l16)*128 + kk);
            acc2[nt2] = __builtin_amdgcn_mfma_f32_16x16x32_bf16(ah2, bh, acc2[nt2], 0, 0, 0);
            acc2[nt2] = __builtin_amdgcn_mfma_f32_16x16x32_bf16(al2, bh, acc2[nt2], 0, 0, 0);
            acc2[nt2] = __builtin_amdgcn_mfma_f32_16x16x32_bf16(ah2, bl, acc2[nt2], 0, 0, 0);
        }
    }

    // ---- epilogue: m = acc2 + hn + b2; out = LN2(m) ----
    #pragma unroll
    for (int r = 0; r < 4; ++r) {
        int n = nb + quad * 4 + r;
        float mv[4];
        #pragma unroll
        for (int nt = 0; nt < 4; ++nt) {
            int c = nt*16 + l16;
            mv[nt] = acc2[nt][r] + hn[r][nt] + bb2[c];
        }
        float s = mv[0] + mv[1] + mv[2] + mv[3];
        #pragma unroll
        for (int o = 1; o < 16; o <<= 1) s += __shfl_xor(s, o);
        float mu = s * (1.0f/64.0f);
        float q = 0.f;
        #pragma unroll
        for (int nt = 0; nt < 4; ++nt) { float t = mv[nt] - mu; q += t*t; }
        #pragma unroll
        for (int o = 1; o < 16; o <<= 1) q += __shfl_xor(q, o);
        float rs = rsqrtf(q * (1.0f/64.0f) + 1e-5f);
        if (n < NN) {
            #pragma unroll
            for (int nt = 0; nt < 4; ++nt) {
                int c = nt*16 + l16;
                out[(size_t)n * 64 + c] = (mv[nt] - mu) * rs * g2[c] + be2[c];
            }
        }
    }
}

extern "C" void kernel_launch(void* const* d_in, const int* in_sizes, int n_in,
                              void* d_out, int out_size, void* d_ws, size_t ws_size,
                              hipStream_t stream) {
    const float* x    = (const float*)d_in[0];
    const int*   ei   = (const int*)d_in[1];
    const float* rf   = (const float*)d_in[2];
    const float* Wp   = (const float*)d_in[3];
    const float* Wn   = (const float*)d_in[4];
    const float* attw = (const float*)d_in[5];
    const float* cf   = (const float*)d_in[6];
    const float* w1   = (const float*)d_in[7];
    const float* b1   = (const float*)d_in[8];
    const float* w2   = (const float*)d_in[9];
    const float* b2   = (const float*)d_in[10];
    const float* g1   = (const float*)d_in[11];
    const float* be1  = (const float*)d_in[12];
    const float* g2   = (const float*)d_in[13];
    const float* be2  = (const float*)d_in[14];
    float* out = (float*)d_out;

    float* ws = (float*)d_ws;
    float*  es1    = ws;                                   // NN
    float*  uv     = es1 + NN;                             // NN*128
    unsigned short* wh = (unsigned short*)(uv + (size_t)NN * 128);   // 24576 u16
    unsigned short* wl = wh + 24576;                                 // 24576 u16
    uint2*  sorted = (uint2*)(wl + 24576);                 // NE uint2
    int*    off    = (int*)(sorted + NE);                  // NN+1
    int*    bcount = off + NN + 1;                         // NBUK
    int*    bbase  = bcount + NBUK;                        // NBUK+1
    int*    bpos   = bbase + NBUK + 1;                     // NBUK
    uint2*  tmp    = (uint2*)uv;                           // alias: uv written later by k4a

    hipMemsetAsync(bcount, 0, NBUK * sizeof(int), stream);

    k0prep    <<<96, 256, 0, stream>>>(Wp, Wn, w1, w2, cf, wh, wl);
    k1_scores <<<(NN+255)/256, 256, 0, stream>>>(x, attw, es1);
    kh_tiled  <<<NTB, 256, 0, stream>>>(ei, bcount);
    ks_bscan  <<<1, 1024, 0, stream>>>(bcount, bbase, bpos);
    kscat1    <<<NTB, 256, 0, stream>>>(ei, rf, bpos, tmp);
    kscat2    <<<NBUK, 256, 0, stream>>>(tmp, bbase, off, sorted);
    k4a_agg   <<<NN/4, 256, 0, stream>>>((const float2*)sorted, off, es1, x, uv);
    k4b5      <<<(NN+63)/64, 256, 0, stream>>>(uv, wh, wl, x, g1, be1, b1, b2, g2, be2, out);
}

// Round 3
// 318.540 us; speedup vs baseline: 1.3933x; 1.0683x over previous
//
#include <hip/hip_runtime.h>
#include <math.h>

#define NN 100000
#define NE 1600000
#define DD 64
#define NBUK 782          // ceil(NN/128), bucket = dst>>7
#define TILE 8192
#define NTB ((NE + TILE - 1) / TILE)   // 196 partition tiles

typedef __attribute__((ext_vector_type(8))) short short8;
typedef __attribute__((ext_vector_type(4))) float f32x4;

__device__ __forceinline__ float gelu_exact(float v) {
    return 0.5f * v * (1.0f + erff(v * 0.7071067811865475f));
}

__device__ __forceinline__ unsigned short f2bf(float f) {   // RNE
    unsigned u = __float_as_uint(f);
    return (unsigned short)((u + 0x7FFFu + ((u >> 16) & 1u)) >> 16);
}
__device__ __forceinline__ float bf2f(unsigned short h) {
    return __uint_as_float((unsigned)h << 16);
}
__device__ __forceinline__ void split8(const float* a, short8& hi, short8& lo) {
    float4 x0 = *(const float4*)a;
    float4 x1 = *(const float4*)(a + 4);
    float v[8] = {x0.x, x0.y, x0.z, x0.w, x1.x, x1.y, x1.z, x1.w};
    #pragma unroll
    for (int i = 0; i < 8; ++i) {
        unsigned short h = f2bf(v[i]);
        hi[i] = (short)h;
        lo[i] = (short)f2bf(v[i] - bf2f(h));
    }
}
__device__ __forceinline__ void split8v(float4 x0, float4 x1, short8& hi, short8& lo) {
    float v[8] = {x0.x, x0.y, x0.z, x0.w, x1.x, x1.y, x1.z, x1.w};
    #pragma unroll
    for (int i = 0; i < 8; ++i) {
        unsigned short h = f2bf(v[i]);
        hi[i] = (short)h;
        lo[i] = (short)f2bf(v[i] - bf2f(h));
    }
}

__device__ __forceinline__ float wave_sum64(float v) {
    #pragma unroll
    for (int o = 32; o > 0; o >>= 1) v += __shfl_xor(v, o);
    return v;
}

// K0P: build bf16 hi/lo split weight buffers
__global__ __launch_bounds__(256) void k0prep(
    const float* __restrict__ Wp, const float* __restrict__ Wn,
    const float* __restrict__ w1, const float* __restrict__ w2,
    const float* __restrict__ cf,
    unsigned short* __restrict__ wh, unsigned short* __restrict__ wl)
{
    int t = blockIdx.x * 256 + threadIdx.x;   // 24576 total
    float alpha = 1.0f / (1.0f + __expf(-cf[0]));
    float beta  = 1.0f - alpha;
    float v;
    if (t < 8192) {
        int d = t >> 7, k = t & 127;
        v = (k < 64) ? alpha * Wp[d * 64 + k] : beta * Wn[d * 64 + (k - 64)];
    } else if (t < 16384) {
        v = w1[t - 8192];
    } else {
        v = w2[t - 16384];
    }
    unsigned short h = f2bf(v);
    wh[t] = h;
    wl[t] = f2bf(v - bf2f(h));
}

// K1: per-node attention projection -> exp(s1). s2[dst] cancels in the
// segment softmax (constant per segment); |s1| <= ~5 so exp never overflows.
__global__ __launch_bounds__(256) void k1_scores(
    const float* __restrict__ x, const float* __restrict__ attw,
    float* __restrict__ es1)
{
    int n = blockIdx.x * 256 + threadIdx.x;
    if (n >= NN) return;
    const float4* x4 = (const float4*)(x + (size_t)n * DD);
    float a = 0.f;
    #pragma unroll
    for (int i = 0; i < DD/4; ++i) {
        float4 v = x4[i];
        a += v.x*attw[4*i+0] + v.y*attw[4*i+1] + v.z*attw[4*i+2] + v.w*attw[4*i+3];
    }
    es1[n] = __expf(a);
}

// KH: tiled coarse histogram — per-block LDS hist, then <=782 global atomics/block
__global__ __launch_bounds__(256) void kh_tiled(
    const int* __restrict__ ei, int* __restrict__ bcount)
{
    __shared__ int hist[NBUK];
    for (int i = threadIdx.x; i < NBUK; i += 256) hist[i] = 0;
    __syncthreads();
    int base = blockIdx.x * TILE;
    int end  = min(base + TILE, NE);
    for (int e = base + threadIdx.x; e < end; e += 256)
        atomicAdd(&hist[ei[NE + e] >> 7], 1);
    __syncthreads();
    for (int i = threadIdx.x; i < NBUK; i += 256) {
        int c = hist[i];
        if (c) atomicAdd(bcount + i, c);
    }
}

// KBS: single-block exclusive scan of 782 bucket counts -> bbase, bpos
__global__ __launch_bounds__(1024) void ks_bscan(
    const int* __restrict__ bcount, int* __restrict__ bbase, int* __restrict__ bpos)
{
    __shared__ int sa[1024], sb[1024];
    int t = threadIdx.x;
    int v = (t < NBUK) ? bcount[t] : 0;
    sa[t] = v;
    __syncthreads();
    int* s = sa; int* d = sb;
    #pragma unroll
    for (int o = 1; o < 1024; o <<= 1) {
        d[t] = s[t] + ((t >= o) ? s[t - o] : 0);
        __syncthreads();
        int* tmp = s; s = d; d = tmp;
    }
    if (t < NBUK) {
        int excl = s[t] - v;
        bbase[t] = excl;
        bpos[t]  = excl;
    }
    if (t == 0) bbase[NBUK] = NE;
}

// KSCAT1: tiled coarse partition (per-block LDS hist -> one reservation atomic
// per (block,bucket) -> LDS-ticket scatter).
__global__ __launch_bounds__(256) void kscat1(
    const int* __restrict__ ei, const float* __restrict__ rf,
    int* __restrict__ bpos, uint2* __restrict__ tmp)
{
    __shared__ int hist[NBUK];
    __shared__ int gbase[NBUK];
    for (int i = threadIdx.x; i < NBUK; i += 256) hist[i] = 0;
    __syncthreads();
    int base = blockIdx.x * TILE;
    int end  = min(base + TILE, NE);
    for (int e = base + threadIdx.x; e < end; e += 256)
        atomicAdd(&hist[ei[NE + e] >> 7], 1);
    __syncthreads();
    for (int i = threadIdx.x; i < NBUK; i += 256) {
        int c = hist[i];
        gbase[i] = c ? atomicAdd(bpos + i, c) : 0;
        hist[i] = 0;                      // reuse as ticket counter
    }
    __syncthreads();
    for (int e = base + threadIdx.x; e < end; e += 256) {
        int src = ei[e];
        int dst = ei[NE + e];
        int b = dst >> 7;
        int t = atomicAdd(&hist[b], 1);
        tmp[gbase[b] + t] =
            make_uint2((unsigned)src | ((unsigned)(dst & 127) << 17),
                       __float_as_uint(rf[e]));
    }
}

// KSCAT2: block-per-bucket fine sort: local histogram -> scan -> off[] + final scatter
__global__ __launch_bounds__(256) void kscat2(
    const uint2* __restrict__ tmp, const int* __restrict__ bbase,
    int* __restrict__ off, uint2* __restrict__ sorted)
{
    __shared__ int hist[128], scn[128], tick[128];
    int b   = blockIdx.x;
    int tid = threadIdx.x;
    int s = bbase[b], e = bbase[b + 1];

    if (tid < 128) { hist[tid] = 0; tick[tid] = 0; }
    __syncthreads();

    for (int i = s + tid; i < e; i += 256)
        atomicAdd(&hist[tmp[i].x >> 17], 1);
    __syncthreads();

    if (tid < 128) scn[tid] = hist[tid];
    __syncthreads();
    #pragma unroll
    for (int o = 1; o < 128; o <<= 1) {
        int v = (tid < 128 && tid >= o) ? scn[tid - o] : 0;
        __syncthreads();
        if (tid < 128) scn[tid] += v;
        __syncthreads();
    }

    int nb0 = b * 128;
    if (tid < 128 && nb0 + tid < NN) off[nb0 + tid] = s + scn[tid] - hist[tid];
    if (b == NBUK - 1 && tid == 0) off[NN] = NE;
    __syncthreads();

    for (int i = s + tid; i < e; i += 256) {
        uint2 pr = tmp[i];
        int l = pr.x >> 17;
        int t = atomicAdd(&tick[l], 1);
        int p = s + (scn[l] - hist[l]) + t;
        sorted[p] = make_uint2(pr.x & 0x1FFFFu, pr.y);
    }
}

// K4A: wave-per-node fused softmax + aggregation, single pass.
__global__ __launch_bounds__(256) void k4a_agg(
    const float2* __restrict__ sorted, const int* __restrict__ off,
    const float* __restrict__ es1,
    const float* __restrict__ x, float* __restrict__ uv)
{
    int lane = threadIdx.x & 63;
    int n = blockIdx.x * 4 + (threadIdx.x >> 6);
    int r0 = off[n], r1 = off[n + 1];

    float den = 0.f, u = 0.f, v = 0.f;
    for (int base = r0; base < r1; base += 64) {
        int idx = base + lane;
        int cnt = min(64, r1 - base);
        int srcl = 0; float rfl = 0.f, el = 0.f;
        if (idx < r1) {
            float2 p = sorted[idx];
            srcl = __float_as_int(p.x);
            rfl  = p.y;
            el   = es1[srcl];
        }
        den += wave_sum64(el);
        int j = 0;
        for (; j + 4 <= cnt; j += 4) {
            int   a0 = __shfl(srcl, j+0), a1 = __shfl(srcl, j+1);
            int   a2 = __shfl(srcl, j+2), a3 = __shfl(srcl, j+3);
            float e0 = __shfl(el, j+0), e1 = __shfl(el, j+1);
            float e2 = __shfl(el, j+2), e3 = __shfl(el, j+3);
            float f0 = __shfl(rfl, j+0), f1 = __shfl(rfl, j+1);
            float f2 = __shfl(rfl, j+2), f3 = __shfl(rfl, j+3);
            float x0 = x[(size_t)a0 * DD + lane];
            float x1 = x[(size_t)a1 * DD + lane];
            float x2 = x[(size_t)a2 * DD + lane];
            float x3 = x[(size_t)a3 * DD + lane];
            v += e0*x0 + e1*x1 + e2*x2 + e3*x3;
            u += e0*f0*x0 + e1*f1*x1 + e2*f2*x2 + e3*f3*x3;
        }
        for (; j < cnt; ++j) {
            int   sj = __shfl(srcl, j);
            float ej = __shfl(el,   j);
            float fj = __shfl(rfl,  j);
            float xv = x[(size_t)sj * DD + lane];
            v += ej * xv;
            u += ej * fj * xv;
        }
    }
    float inv = (r1 > r0) ? 1.f / den : 0.f;
    uv[(size_t)n * 2*DD + lane]      = u * inv;
    uv[(size_t)n * 2*DD + DD + lane] = v * inv;
}

// K4B5 v2: fused epilogue chain with PHASE-STAGED LDS WEIGHTS.
// Per 64-node block: stage Bmix -> GEMM0 -> LN1 (in-reg, h kept) -> restage w1
// -> GEMM1 (full 128 cols) -> gelu -> G tile (LDS, union with h) -> restage w2
// -> GEMM2 -> +h residual +b2 -> LN2 -> out.
// Weight B-fragments come from LDS (was: ~96 serialized L2/L3 round-trips per
// wave -> the measured 103K-cycle per-wave stall). Padded strides 136/72 u16
// put the 16 rows of each quad on all 8 b128 bank-slots (optimal).
// LDS = 2*18432 (wt) + 33792 (tile) = 70656 B -> 2 blocks/CU.
__global__ __launch_bounds__(256, 2) void k4b5(
    const float* __restrict__ uv,
    const unsigned short* __restrict__ wh, const unsigned short* __restrict__ wl,
    const float* __restrict__ x,
    const float* __restrict__ g1, const float* __restrict__ be1,
    const float* __restrict__ bb1, const float* __restrict__ bb2,
    const float* __restrict__ g2, const float* __restrict__ be2,
    float* __restrict__ out)
{
    __shared__ unsigned short WHs[9216];   // max(64*136, 128*72) u16
    __shared__ unsigned short WLs[9216];
    __shared__ float Gt[4][16][132];       // per-wave tile; h (cols<64) then G

    int tid  = threadIdx.x;
    int lane = tid & 63;
    int wv   = tid >> 6;
    int quad = lane >> 4, l16 = lane & 15;
    int nb = blockIdx.x * 64 + wv * 16;
    const float4* arow4 = (const float4*)(uv + (size_t)min(nb + l16, NN - 1) * 128);

    // ---- issue all long-latency global loads upfront (hide under staging) ----
    float4 av[8];
    #pragma unroll
    for (int ks = 0; ks < 4; ++ks) {
        av[2*ks]   = arow4[ks*8 + quad*2];
        av[2*ks+1] = arow4[ks*8 + quad*2 + 1];
    }
    float xr[4][4];
    #pragma unroll
    for (int r = 0; r < 4; ++r) {
        size_t nld = (size_t)min(nb + quad*4 + r, NN - 1) * 64;
        #pragma unroll
        for (int nt = 0; nt < 4; ++nt) xr[r][nt] = x[nld + nt*16 + l16];
    }
    float g1v[4], be1v[4], bb2v[4], g2v[4], be2v[4], bb1v[8];
    #pragma unroll
    for (int nt = 0; nt < 4; ++nt) {
        int c = nt*16 + l16;
        g1v[nt] = g1[c];  be1v[nt] = be1[c];
        bb2v[nt] = bb2[c]; g2v[nt] = g2[c]; be2v[nt] = be2[c];
    }
    #pragma unroll
    for (int t = 0; t < 8; ++t) bb1v[t] = bb1[t*16 + l16];

    // ---- stage Bmix: 64 rows x 128 cols, padded stride 136 u16 ----
    #pragma unroll
    for (int k = 0; k < 4; ++k) {
        int i = tid + k*256;
        int row = i >> 4, col = (i & 15) * 8;
        *(short8*)&WHs[row*136 + col] = *(const short8*)&wh[i*8];
        *(short8*)&WLs[row*136 + col] = *(const short8*)&wl[i*8];
    }
    __syncthreads();

    // ---- GEMM0: uv[16x128] @ Bmix^T -> 16x64 ----
    f32x4 acc0[4] = {};
    #pragma unroll
    for (int ks = 0; ks < 4; ++ks) {
        int k0 = ks * 32 + quad * 8;
        short8 ah, al;
        split8v(av[2*ks], av[2*ks+1], ah, al);
        #pragma unroll
        for (int nt = 0; nt < 4; ++nt) {
            short8 bh = *(const short8*)&WHs[(nt*16 + l16)*136 + k0];
            short8 bl = *(const short8*)&WLs[(nt*16 + l16)*136 + k0];
            acc0[nt] = __builtin_amdgcn_mfma_f32_16x16x32_bf16(ah, bh, acc0[nt], 0, 0, 0);
            acc0[nt] = __builtin_amdgcn_mfma_f32_16x16x32_bf16(al, bh, acc0[nt], 0, 0, 0);
            acc0[nt] = __builtin_amdgcn_mfma_f32_16x16x32_bf16(ah, bl, acc0[nt], 0, 0, 0);
        }
    }

    // ---- gelu + residual + LN1; keep hn in regs, stage h into tile ----
    float hn[4][4];
    #pragma unroll
    for (int r = 0; r < 4; ++r) {
        float hv[4];
        #pragma unroll
        for (int nt = 0; nt < 4; ++nt)
            hv[nt] = gelu_exact(acc0[nt][r]) + xr[r][nt];
        float s = hv[0] + hv[1] + hv[2] + hv[3];
        #pragma unroll
        for (int o = 1; o < 16; o <<= 1) s += __shfl_xor(s, o);
        float mu = s * (1.0f/64.0f);
        float q = 0.f;
        #pragma unroll
        for (int nt = 0; nt < 4; ++nt) { float t = hv[nt] - mu; q += t*t; }
        #pragma unroll
        for (int o = 1; o < 16; o <<= 1) q += __shfl_xor(q, o);
        float rs = rsqrtf(q * (1.0f/64.0f) + 1e-5f);
        #pragma unroll
        for (int nt = 0; nt < 4; ++nt) {
            hn[r][nt] = (hv[nt] - mu) * rs * g1v[nt] + be1v[nt];
            Gt[wv][quad*4 + r][nt*16 + l16] = hn[r][nt];
        }
    }
    __syncthreads();   // all waves done reading Bmix from LDS

    // ---- restage w1: 128 rows x 64 cols, padded stride 72 u16 ----
    #pragma unroll
    for (int k = 0; k < 4; ++k) {
        int i = tid + k*256;
        int row = i >> 3, col = (i & 7) * 8;
        *(short8*)&WHs[row*72 + col] = *(const short8*)&wh[8192 + i*8];
        *(short8*)&WLs[row*72 + col] = *(const short8*)&wl[8192 + i*8];
    }
    __syncthreads();

    // ---- A1 fragments from h rows (wave-private tile) ----
    short8 ah1[2], al1[2];
    #pragma unroll
    for (int ks = 0; ks < 2; ++ks)
        split8(&Gt[wv][l16][ks*32 + quad*8], ah1[ks], al1[ks]);

    // ---- GEMM1: h[16x64] @ w1^T -> 16x128, gelu -> G tile ----
    f32x4 acc1[8] = {};
    #pragma unroll
    for (int ks = 0; ks < 2; ++ks) {
        int k0 = ks * 32 + quad * 8;
        #pragma unroll
        for (int nt1 = 0; nt1 < 8; ++nt1) {
            short8 bh = *(const short8*)&WHs[(nt1*16 + l16)*72 + k0];
            short8 bl = *(const short8*)&WLs[(nt1*16 + l16)*72 + k0];
            acc1[nt1] = __builtin_amdgcn_mfma_f32_16x16x32_bf16(ah1[ks], bh, acc1[nt1], 0, 0, 0);
            acc1[nt1] = __builtin_amdgcn_mfma_f32_16x16x32_bf16(al1[ks], bh, acc1[nt1], 0, 0, 0);
            acc1[nt1] = __builtin_amdgcn_mfma_f32_16x16x32_bf16(ah1[ks], bl, acc1[nt1], 0, 0, 0);
        }
    }
    #pragma unroll
    for (int nt1 = 0; nt1 < 8; ++nt1) {
        float b1v = bb1v[nt1];
        #pragma unroll
        for (int r = 0; r < 4; ++r)
            Gt[wv][quad*4 + r][nt1*16 + l16] = gelu_exact(acc1[nt1][r] + b1v);
    }
    __syncthreads();   // all waves done reading w1 from LDS

    // ---- restage w2: 64 rows x 128 cols, padded stride 136 u16 ----
    #pragma unroll
    for (int k = 0; k < 4; ++k) {
        int i = tid + k*256;
        int row = i >> 4, col = (i & 15) * 8;
        *(short8*)&WHs[row*136 + col] = *(const short8*)&wh[16384 + i*8];
        *(short8*)&WLs[row*136 + col] = *(const short8*)&wl[16384 + i*8];
    }
    __syncthreads();

    // ---- GEMM2: G[16x128] @ w2^T -> 16x64 ----
    f32x4 acc2[4] = {};
    #pragma unroll
    for (int ks = 0; ks < 4; ++ks) {
        int k0 = ks * 32 + quad * 8;
        short8 ah2, al2;
        split8(&Gt[wv][l16][k0], ah2, al2);
        #pragma unroll
        for (int nt2 = 0; nt2 < 4; ++nt2) {
            short8 bh = *(const short8*)&WHs[(nt2*16 + l16)*136 + k0];
            short8 bl = *(const short8*)&WLs[(nt2*16 + l16)*136 + k0];
            acc2[nt2] = __builtin_amdgcn_mfma_f32_16x16x32_bf16(ah2, bh, acc2[nt2], 0, 0, 0);
            acc2[nt2] = __builtin_amdgcn_mfma_f32_16x16x32_bf16(al2, bh, acc2[nt2], 0, 0, 0);
            acc2[nt2] = __builtin_amdgcn_mfma_f32_16x16x32_bf16(ah2, bl, acc2[nt2], 0, 0, 0);
        }
    }

    // ---- epilogue: m = acc2 + hn + b2; out = LN2(m) ----
    #pragma unroll
    for (int r = 0; r < 4; ++r) {
        int n = nb + quad * 4 + r;
        float mv[4];
        #pragma unroll
        for (int nt = 0; nt < 4; ++nt)
            mv[nt] = acc2[nt][r] + hn[r][nt] + bb2v[nt];
        float s = mv[0] + mv[1] + mv[2] + mv[3];
        #pragma unroll
        for (int o = 1; o < 16; o <<= 1) s += __shfl_xor(s, o);
        float mu = s * (1.0f/64.0f);
        float q = 0.f;
        #pragma unroll
        for (int nt = 0; nt < 4; ++nt) { float t = mv[nt] - mu; q += t*t; }
        #pragma unroll
        for (int o = 1; o < 16; o <<= 1) q += __shfl_xor(q, o);
        float rs = rsqrtf(q * (1.0f/64.0f) + 1e-5f);
        if (n < NN) {
            #pragma unroll
            for (int nt = 0; nt < 4; ++nt) {
                int c = nt*16 + l16;
                out[(size_t)n * 64 + c] = (mv[nt] - mu) * rs * g2v[nt] + be2v[nt];
            }
        }
    }
}

extern "C" void kernel_launch(void* const* d_in, const int* in_sizes, int n_in,
                              void* d_out, int out_size, void* d_ws, size_t ws_size,
                              hipStream_t stream) {
    const float* x    = (const float*)d_in[0];
    const int*   ei   = (const int*)d_in[1];
    const float* rf   = (const float*)d_in[2];
    const float* Wp   = (const float*)d_in[3];
    const float* Wn   = (const float*)d_in[4];
    const float* attw = (const float*)d_in[5];
    const float* cf   = (const float*)d_in[6];
    const float* w1   = (const float*)d_in[7];
    const float* b1   = (const float*)d_in[8];
    const float* w2   = (const float*)d_in[9];
    const float* b2   = (const float*)d_in[10];
    const float* g1   = (const float*)d_in[11];
    const float* be1  = (const float*)d_in[12];
    const float* g2   = (const float*)d_in[13];
    const float* be2  = (const float*)d_in[14];
    float* out = (float*)d_out;

    float* ws = (float*)d_ws;
    float*  es1    = ws;                                   // NN
    float*  uv     = es1 + NN;                             // NN*128
    unsigned short* wh = (unsigned short*)(uv + (size_t)NN * 128);   // 24576 u16
    unsigned short* wl = wh + 24576;                                 // 24576 u16
    uint2*  sorted = (uint2*)(wl + 24576);                 // NE uint2
    int*    off    = (int*)(sorted + NE);                  // NN+1
    int*    bcount = off + NN + 1;                         // NBUK
    int*    bbase  = bcount + NBUK;                        // NBUK+1
    int*    bpos   = bbase + NBUK + 1;                     // NBUK
    uint2*  tmp    = (uint2*)uv;                           // alias: uv written later by k4a

    hipMemsetAsync(bcount, 0, NBUK * sizeof(int), stream);

    k0prep    <<<96, 256, 0, stream>>>(Wp, Wn, w1, w2, cf, wh, wl);
    k1_scores <<<(NN+255)/256, 256, 0, stream>>>(x, attw, es1);
    kh_tiled  <<<NTB, 256, 0, stream>>>(ei, bcount);
    ks_bscan  <<<1, 1024, 0, stream>>>(bcount, bbase, bpos);
    kscat1    <<<NTB, 256, 0, stream>>>(ei, rf, bpos, tmp);
    kscat2    <<<NBUK, 256, 0, stream>>>(tmp, bbase, off, sorted);
    k4a_agg   <<<NN/4, 256, 0, stream>>>((const float2*)sorted, off, es1, x, uv);
    k4b5      <<<(NN+63)/64, 256, 0, stream>>>(uv, wh, wl, x, g1, be1, b1, b2, g2, be2, out);
}